// Round 9
// baseline (328.943 us; speedup 1.0000x reference)
//
#include <hip/hip_runtime.h>
#include <math.h>

#define B_ 8
#define T_ 64
#define N_ 196
#define D_ 768
#define K_ 8
#define FEAT 40
#define EPSF 1e-6f

constexpr int ROWS = B_ * T_ * N_;                 // 100352
constexpr long long HSIZE = (long long)ROWS * D_;  // 77070336
constexpr int QPR = D_ / 4;                        // 192 float4 per row
constexpr unsigned RSTRIDE = (unsigned)N_ * QPR;   // 37632 v4f per t-step

typedef float v4f __attribute__((ext_vector_type(4)));

__device__ __forceinline__ float wredux(float v) {
#pragma unroll
    for (int off = 32; off > 0; off >>= 1)
        v += __shfl_xor(v, off, 64);
    return v;
}

__device__ __forceinline__ float dot4(v4f a, v4f b) {
    return a.x * b.x + a.y * b.y + a.z * b.z + a.w * b.w;
}

// W = softplus(W_raw) -> d_out tail;  beta_s = sigmoid(beta) -> ws
__global__ __launch_bounds__(256) void k_wsp(const float* __restrict__ wraw,
                                             const float* __restrict__ beta,
                                             float* __restrict__ wout,
                                             float* __restrict__ beta_s) {
    int i = blockIdx.x * blockDim.x + threadIdx.x;
    if (i < FEAT * D_) {
        float xw = wraw[i];
        wout[i] = fmaxf(xw, 0.0f) + log1pf(expf(-fabsf(xw)));
    }
    if (i < D_) beta_s[i] = 1.0f / (1.0f + expf(-beta[i]));
}

// Fused, one block per (b,n), 256 threads = 4 waves, wave w owns rows
// t = w*16 .. w*16+15 processed 2 at a time.
// proj_W lives in LDS (k-outer dot) so the vmem pipe carries ONLY the x
// stream (round-8 failure: compiler remat'd 96-reg u from L1, 24 extra
// vmem ops/row). launch_bounds(256,4): 128-reg budget, ~90 needed.
__global__ __launch_bounds__(256, 4)
void k_fused(const float* __restrict__ x,
             const float* __restrict__ mask,
             const float* __restrict__ pw,
             const float* __restrict__ wsp,
             const float* __restrict__ beta_s,
             float* __restrict__ h) {
    __shared__ float uld[K_ * D_];        // 24 KB proj_W
    __shared__ float vpart[T_][K_ + 1];   // pad: odd stride, conflict-free
    __shared__ float sf[FEAT];
    __shared__ float ylds[D_];
    __shared__ float smask[T_];

    const int tid  = threadIdx.x;
    const int lane = tid & 63;
    const int w    = tid >> 6;
    const int bn   = blockIdx.x;
    const int b    = bn / N_;
    const int n    = bn - b * N_;

    const v4f* x4 = (const v4f*)x;
    const unsigned base0 = (unsigned)((b * T_ + w * 16) * N_ + n) * QPR;

    // issue first 2-row group's x loads BEFORE the staging barrier
    unsigned qX = base0;
    v4f X[2][3];
#pragma unroll
    for (int r = 0; r < 2; r++) {
        unsigned q = qX + r * RSTRIDE;
        X[r][0] = x4[q + lane];
        X[r][1] = x4[q + 64 + lane];
        X[r][2] = x4[q + 128 + lane];
    }

    // stage proj_W into LDS (1536 v4f, 6 per thread, coalesced) + mask col
    {
        const v4f* p4 = (const v4f*)pw;
        v4f* u4w = (v4f*)uld;
#pragma unroll
        for (int i = 0; i < 6; i++)
            u4w[tid + 256 * i] = p4[tid + 256 * i];
    }
    if (tid < T_) smask[tid] = mask[(b * T_ + tid) * N_ + n];
    __syncthreads();

    // ---- Phase A: 8 groups of 2 rows, next group prefetched during dots ----
    const v4f* u4 = (const v4f*)uld;
#pragma unroll 1
    for (int g = 0; g < 8; ++g) {
        v4f C[2][3];
#pragma unroll
        for (int r = 0; r < 2; r++)
#pragma unroll
            for (int c = 0; c < 3; c++)
                C[r][c] = X[r][c];
        if (g < 7) {
            qX += 2 * RSTRIDE;
#pragma unroll
            for (int r = 0; r < 2; r++) {
                unsigned q = qX + r * RSTRIDE;
                X[r][0] = x4[q + lane];
                X[r][1] = x4[q + 64 + lane];
                X[r][2] = x4[q + 128 + lane];
            }
        }
        float acc[2][K_];
#pragma unroll
        for (int k = 0; k < K_; k++) {
            v4f u0 = u4[k * 192 + lane];
            v4f u1 = u4[k * 192 + 64 + lane];
            v4f u2 = u4[k * 192 + 128 + lane];
#pragma unroll
            for (int r = 0; r < 2; r++)
                acc[r][k] = dot4(C[r][0], u0) + dot4(C[r][1], u1) + dot4(C[r][2], u2);
        }
#pragma unroll
        for (int r = 0; r < 2; r++) {
#pragma unroll
            for (int k = 0; k < K_; k++) {
                float a = acc[r][k];
                a += __shfl_xor(a, 1, 64);
                a += __shfl_xor(a, 2, 64);
                a += __shfl_xor(a, 4, 64);
                acc[r][k] = a;
            }
            const int rr = lane & 7;
            float val = (rr & 4) ? ((rr & 2) ? ((rr & 1) ? acc[r][7] : acc[r][6])
                                             : ((rr & 1) ? acc[r][5] : acc[r][4]))
                                 : ((rr & 2) ? ((rr & 1) ? acc[r][3] : acc[r][2])
                                             : ((rr & 1) ? acc[r][1] : acc[r][0]));
            val += __shfl_xor(val, 8, 64);
            val += __shfl_xor(val, 16, 64);
            val += __shfl_xor(val, 32, 64);
            if (lane < K_) vpart[w * 16 + g * 2 + r][lane] = val;
        }
    }
    __syncthreads();

    // ---- Phase B: wave w owns k = w and k = w+4; lane = t ----
#pragma unroll
    for (int kk = 0; kk < 2; kk++) {
        const int k = w + kk * 4;
        float v = vpart[lane][k] * smask[lane];
        float s2  = wredux(v * v);
        float rms = sqrtf(s2 * (1.0f / T_) + EPSF);
        float vb  = 2.5f * tanhf(v / (rms + EPSF));
        const float PI = 3.14159265358979323846f;
        float ph = PI * ((float)lane + 0.5f) / (float)T_;
        float c1 = cosf(ph), c2 = cosf(2.0f * ph);
        float n1 = wredux(c1 * c1), n2 = wredux(c2 * c2);
        float S1 = wredux(vb), Sc1 = wredux(vb * c1);
        float Sc2 = wredux(vb * c2), Sq = wredux(vb * vb);
        if (lane == 0) {
            float* o = sf + k * 5;
            o[0] = S1 / (8.0f + EPSF);
            o[1] = Sc1 / (sqrtf(n1) + EPSF);
            o[2] = Sc2 / (sqrtf(n2) + EPSF);
            o[3] = S1 * (1.0f / T_);
            o[4] = sqrtf(Sq * (1.0f / T_) + EPSF);
        }
    }
    __syncthreads();

    // ---- Phase C: ylds[d] = beta_s[d] * sum_f sf[f]*wsp[f][d] (L2-hot) ----
    for (int d = tid; d < D_; d += 256) {
        float a0 = 0.f, a1 = 0.f;
#pragma unroll
        for (int f = 0; f < FEAT; f += 2) {
            a0 += sf[f]     * wsp[f * D_ + d];
            a1 += sf[f + 1] * wsp[(f + 1) * D_ + d];
        }
        ylds[d] = (a0 + a1) * beta_s[d];
    }
    __syncthreads();

    // ---- Phase D: h = x + m*ylds; 2-row groups, prefetched; nt load+store
    // (x reload is L3-hot and dead-after-use; h is write-once) ----
    const v4f* y4 = (const v4f*)ylds;
    const v4f y0 = y4[lane], y1 = y4[64 + lane], y2 = y4[128 + lane];
    v4f* h4 = (v4f*)h;
    unsigned qD = base0;
    v4f P[2][3];
#pragma unroll
    for (int r = 0; r < 2; r++) {
        unsigned q = qD + r * RSTRIDE;
        P[r][0] = __builtin_nontemporal_load(x4 + q + lane);
        P[r][1] = __builtin_nontemporal_load(x4 + q + 64 + lane);
        P[r][2] = __builtin_nontemporal_load(x4 + q + 128 + lane);
    }
#pragma unroll 1
    for (int g = 0; g < 8; ++g) {
        v4f C[2][3];
#pragma unroll
        for (int r = 0; r < 2; r++)
#pragma unroll
            for (int c = 0; c < 3; c++)
                C[r][c] = P[r][c];
        const unsigned qs = qD;
        if (g < 7) {
            qD += 2 * RSTRIDE;
#pragma unroll
            for (int r = 0; r < 2; r++) {
                unsigned q = qD + r * RSTRIDE;
                P[r][0] = __builtin_nontemporal_load(x4 + q + lane);
                P[r][1] = __builtin_nontemporal_load(x4 + q + 64 + lane);
                P[r][2] = __builtin_nontemporal_load(x4 + q + 128 + lane);
            }
        }
#pragma unroll
        for (int r = 0; r < 2; r++) {
            const float m = smask[w * 16 + g * 2 + r];
            unsigned q = qs + r * RSTRIDE;
            __builtin_nontemporal_store(C[r][0] + m * y0, h4 + q + lane);
            __builtin_nontemporal_store(C[r][1] + m * y1, h4 + q + 64 + lane);
            __builtin_nontemporal_store(C[r][2] + m * y2, h4 + q + 128 + lane);
        }
    }
}

extern "C" void kernel_launch(void* const* d_in, const int* in_sizes, int n_in,
                              void* d_out, int out_size, void* d_ws, size_t ws_size,
                              hipStream_t stream) {
    const float* x    = (const float*)d_in[0];
    const float* mask = (const float*)d_in[1];
    const float* pw   = (const float*)d_in[2];
    const float* wraw = (const float*)d_in[3];
    const float* beta = (const float*)d_in[4];

    float* h    = (float*)d_out;
    float* wout = h + HSIZE;
    float* beta_s = (float*)d_ws;   // [768]

    hipLaunchKernelGGL(k_wsp, dim3((FEAT * D_ + 255) / 256), dim3(256), 0, stream,
                       wraw, beta, wout, beta_s);
    hipLaunchKernelGGL(k_fused, dim3(B_ * N_), dim3(256), 0, stream,
                       x, mask, pw, wout, beta_s, h);
}

// Round 10
// 174.856 us; speedup vs baseline: 1.8812x; 1.8812x over previous
//
#include <hip/hip_runtime.h>
#include <math.h>

#define B_ 8
#define T_ 64
#define N_ 196
#define D_ 768
#define K_ 8
#define FEAT 40
#define EPSF 1e-6f

constexpr int ROWS = B_ * T_ * N_;                 // 100352
constexpr long long HSIZE = (long long)ROWS * D_;  // 77070336
constexpr int QPR = D_ / 4;                        // 192 float4 per row
constexpr unsigned RSTRIDE = (unsigned)N_ * QPR;   // 37632 v4f per t-step

typedef float v4f __attribute__((ext_vector_type(4)));

__device__ __forceinline__ float wredux(float v) {
#pragma unroll
    for (int off = 32; off > 0; off >>= 1)
        v += __shfl_xor(v, off, 64);
    return v;
}

__device__ __forceinline__ float dot4(v4f a, v4f b) {
    return a.x * b.x + a.y * b.y + a.z * b.z + a.w * b.w;
}

// W = softplus(W_raw) -> d_out tail;  beta_s = sigmoid(beta) -> ws
__global__ __launch_bounds__(256) void k_wsp(const float* __restrict__ wraw,
                                             const float* __restrict__ beta,
                                             float* __restrict__ wout,
                                             float* __restrict__ beta_s) {
    int i = blockIdx.x * blockDim.x + threadIdx.x;
    if (i < FEAT * D_) {
        float xw = wraw[i];
        wout[i] = fmaxf(xw, 0.0f) + log1pf(expf(-fabsf(xw)));
    }
    if (i < D_) beta_s[i] = 1.0f / (1.0f + expf(-beta[i]));
}

// Fused, one block per (b,n), 256 threads = 4 waves.
// Phase A (k-split): wave w holds proj_W rows k=2w,2w+1 in 24 REGISTERS
// (fits the ~72-VGPR budget the allocator actually grants — rounds 7-9
// showed 96-reg u always gets remat'd/spilled) and sweeps ALL 64 rows.
// The 4 waves re-read the same x rows in lock-step (barrier every 8 rows)
// so 3/4 of reads are L1/L2 hits; HBM sees x exactly once.
__global__ __launch_bounds__(256)
void k_fused(const float* __restrict__ x,
             const float* __restrict__ mask,
             const float* __restrict__ pw,
             const float* __restrict__ wsp,
             const float* __restrict__ beta_s,
             float* __restrict__ h) {
    __shared__ float vpart[T_][K_ + 1];   // pad: odd stride, conflict-free
    __shared__ float sf[FEAT];
    __shared__ float ylds[D_];
    __shared__ float smask[T_];

    const int tid  = threadIdx.x;
    const int lane = tid & 63;
    const int w    = tid >> 6;
    const int bn   = blockIdx.x;
    const int b    = bn / N_;
    const int n    = bn - b * N_;

    // u-slice for this wave's two k's: 6 v4f = 24 VGPRs, loop-invariant
    v4f u[2][3];
#pragma unroll
    for (int kk = 0; kk < 2; kk++)
#pragma unroll
        for (int c = 0; c < 3; c++)
            u[kk][c] = *(const v4f*)(pw + (2 * w + kk) * D_ + c * 256 + lane * 4);

    if (tid < T_) smask[tid] = mask[(b * T_ + tid) * N_ + n];

    // ---- Phase A: all 64 rows, 2-deep pipelined, 2 k's per wave ----
    const v4f* x4 = (const v4f*)x;
    const unsigned rowq0 = (unsigned)((b * T_) * N_ + n) * QPR;
    unsigned qn = rowq0;
    v4f n0 = x4[qn + lane];
    v4f n1 = x4[qn + 64 + lane];
    v4f n2 = x4[qn + 128 + lane];
#pragma unroll 1
    for (int t = 0; t < T_; t++) {
        v4f c0 = n0, c1 = n1, c2 = n2;
        if (t < T_ - 1) {
            qn += RSTRIDE;
            n0 = x4[qn + lane];
            n1 = x4[qn + 64 + lane];
            n2 = x4[qn + 128 + lane];
        }
        float a0 = dot4(c0, u[0][0]) + dot4(c1, u[0][1]) + dot4(c2, u[0][2]);
        float a1 = dot4(c0, u[1][0]) + dot4(c1, u[1][1]) + dot4(c2, u[1][2]);
        // batched 2-way reduce: pair-sum each, select by lane&1, 5 butterflies
        a0 += __shfl_xor(a0, 1, 64);
        a1 += __shfl_xor(a1, 1, 64);
        float val = (lane & 1) ? a1 : a0;
        val += __shfl_xor(val, 2, 64);
        val += __shfl_xor(val, 4, 64);
        val += __shfl_xor(val, 8, 64);
        val += __shfl_xor(val, 16, 64);
        val += __shfl_xor(val, 32, 64);
        if (lane < 2) vpart[t][2 * w + lane] = val;
        if ((t & 7) == 7) __syncthreads();   // bound wave skew -> L1 reuse
    }
    __syncthreads();

    // ---- Phase B: wave w owns k = w and k = w+4; lane = t ----
#pragma unroll
    for (int kk = 0; kk < 2; kk++) {
        const int k = w + kk * 4;
        float v = vpart[lane][k] * smask[lane];
        float s2  = wredux(v * v);
        float rms = sqrtf(s2 * (1.0f / T_) + EPSF);
        float vb  = 2.5f * tanhf(v / (rms + EPSF));
        const float PI = 3.14159265358979323846f;
        float ph = PI * ((float)lane + 0.5f) / (float)T_;
        float c1 = cosf(ph), c2 = cosf(2.0f * ph);
        float n1 = wredux(c1 * c1), n2 = wredux(c2 * c2);
        float S1 = wredux(vb), Sc1 = wredux(vb * c1);
        float Sc2 = wredux(vb * c2), Sq = wredux(vb * vb);
        if (lane == 0) {
            float* o = sf + k * 5;
            o[0] = S1 / (8.0f + EPSF);
            o[1] = Sc1 / (sqrtf(n1) + EPSF);
            o[2] = Sc2 / (sqrtf(n2) + EPSF);
            o[3] = S1 * (1.0f / T_);
            o[4] = sqrtf(Sq * (1.0f / T_) + EPSF);
        }
    }
    __syncthreads();

    // ---- Phase C: ylds[d] = beta_s[d] * sum_f sf[f]*wsp[f][d] (L2-hot) ----
    for (int d = tid; d < D_; d += 256) {
        float a0 = 0.f, a1 = 0.f;
#pragma unroll
        for (int f = 0; f < FEAT; f += 2) {
            a0 += sf[f]     * wsp[f * D_ + d];
            a1 += sf[f + 1] * wsp[(f + 1) * D_ + d];
        }
        ylds[d] = (a0 + a1) * beta_s[d];
    }
    __syncthreads();

    // ---- Phase D: rows t = w*16..w*16+15; x reload L3-hot; nt stores ----
    const v4f* y4 = (const v4f*)ylds;
    const v4f y0 = y4[lane], y1 = y4[64 + lane], y2 = y4[128 + lane];
    v4f* h4 = (v4f*)h;
    unsigned qD = (unsigned)((b * T_ + w * 16) * N_ + n) * QPR;
    v4f d0 = __builtin_nontemporal_load(x4 + qD + lane);
    v4f d1 = __builtin_nontemporal_load(x4 + qD + 64 + lane);
    v4f d2 = __builtin_nontemporal_load(x4 + qD + 128 + lane);
#pragma unroll 1
    for (int j = 0; j < 16; j++) {
        v4f c0 = d0, c1 = d1, c2 = d2;
        const unsigned qc = qD;
        if (j < 15) {
            qD += RSTRIDE;
            d0 = __builtin_nontemporal_load(x4 + qD + lane);
            d1 = __builtin_nontemporal_load(x4 + qD + 64 + lane);
            d2 = __builtin_nontemporal_load(x4 + qD + 128 + lane);
        }
        const float m = smask[w * 16 + j];
        __builtin_nontemporal_store(c0 + m * y0, h4 + qc + lane);
        __builtin_nontemporal_store(c1 + m * y1, h4 + qc + 64 + lane);
        __builtin_nontemporal_store(c2 + m * y2, h4 + qc + 128 + lane);
    }
}

extern "C" void kernel_launch(void* const* d_in, const int* in_sizes, int n_in,
                              void* d_out, int out_size, void* d_ws, size_t ws_size,
                              hipStream_t stream) {
    const float* x    = (const float*)d_in[0];
    const float* mask = (const float*)d_in[1];
    const float* pw   = (const float*)d_in[2];
    const float* wraw = (const float*)d_in[3];
    const float* beta = (const float*)d_in[4];

    float* h    = (float*)d_out;
    float* wout = h + HSIZE;
    float* beta_s = (float*)d_ws;   // [768]

    hipLaunchKernelGGL(k_wsp, dim3((FEAT * D_ + 255) / 256), dim3(256), 0, stream,
                       wraw, beta, wout, beta_s);
    hipLaunchKernelGGL(k_fused, dim3(B_ * N_), dim3(256), 0, stream,
                       x, mask, pw, wout, beta_s, h);
}